// Round 1
// baseline (545.568 us; speedup 1.0000x reference)
//
#include <hip/hip_runtime.h>

// Problem constants (B=4, S=2048, D=1024, C=16, N=2048, sub=64, K=1)
constexpr int BS    = 8192;   // B*S tokens
constexpr int DTOT  = 1024;
constexpr int CCH   = 16;     // chunks
constexpr int NCODE = 2048;   // codewords per chunk
constexpr int SUB   = 64;     // sub-dim
constexpr int K4    = SUB / 4;

constexpr int MT = 128;       // token tile
constexpr int NT = 128;       // codeword tile

// LDS plan (64 KB total, aliased):
//   main phase: xs[16][128] float4 (32 KB) | cs[16][128] float4 (32 KB)
//   reduce phase (aliases xs region): rs[16][128] f32 (8 KB) + ri[16][128] i32 (8 KB) + bfin[128] i32

__global__ __launch_bounds__(256, 2)
void vq_argmin_gather(const float* __restrict__ x,
                      const float* __restrict__ cb,
                      float* __restrict__ out)
{
    __shared__ __align__(16) char smraw[65536];
    float4 (*xs)[MT] = reinterpret_cast<float4(*)[MT]>(smraw);
    float4 (*cs)[NT] = reinterpret_cast<float4(*)[NT]>(smraw + 32768);
    float  (*rs)[MT] = reinterpret_cast<float(*)[MT]>(smraw);
    int    (*ri)[MT] = reinterpret_cast<int(*)[MT]>(smraw + 8192);
    int    *bfin     = reinterpret_cast<int*>(smraw + 16384);

    const int tid   = threadIdx.x;
    const int tx    = tid & 15;       // token-column group
    const int ty    = tid >> 4;       // codeword-column group
    const int c     = blockIdx.y;
    const int mbase = blockIdx.x * MT;

    const float4* xg = reinterpret_cast<const float4*>(x);
    const float4* cg = reinterpret_cast<const float4*>(cb);

    // ---- stage x tile: xs[k4][m] = 4 consecutive k-values of token (mbase+m)
    {
        const int k4    = tid & 15;
        const int mrow0 = tid >> 4;
#pragma unroll
        for (int i = 0; i < 8; ++i) {
            const int m = i * 16 + mrow0;
            xs[k4][m] = xg[(size_t)(mbase + m) * (DTOT / 4) + c * K4 + k4];
        }
    }

    float best[8];
    int   bidx[8];
#pragma unroll
    for (int ii = 0; ii < 8; ++ii) { best[ii] = 3.4e38f; bidx[ii] = 0; }

    for (int nt = 0; nt < NCODE / NT; ++nt) {
        __syncthreads();   // previous tile's readers done before overwrite
        // ---- stage codeword tile: cs[k4][n]
        {
            const int k4    = tid & 15;
            const int nrow0 = tid >> 4;
#pragma unroll
            for (int i = 0; i < 8; ++i) {
                const int n = i * 16 + nrow0;
                cs[k4][n] = cg[((size_t)c * NCODE + nt * NT + n) * K4 + k4];
            }
        }
        __syncthreads();

        float acc[8][8];
        float csq[8];
#pragma unroll
        for (int ii = 0; ii < 8; ++ii)
#pragma unroll
            for (int jj = 0; jj < 8; ++jj) acc[ii][jj] = 0.f;
#pragma unroll
        for (int jj = 0; jj < 8; ++jj) csq[jj] = 0.f;

#pragma unroll 2
        for (int k4 = 0; k4 < K4; ++k4) {
            float4 xv[8], cv[8];
#pragma unroll
            for (int ii = 0; ii < 8; ++ii) xv[ii] = xs[k4][tx + 16 * ii];
#pragma unroll
            for (int jj = 0; jj < 8; ++jj) cv[jj] = cs[k4][ty + 16 * jj];

            // codeword squared norms (per-n, shared across ii)
#pragma unroll
            for (int jj = 0; jj < 8; ++jj) {
                csq[jj] = fmaf(cv[jj].x, cv[jj].x, csq[jj]);
                csq[jj] = fmaf(cv[jj].y, cv[jj].y, csq[jj]);
                csq[jj] = fmaf(cv[jj].z, cv[jj].z, csq[jj]);
                csq[jj] = fmaf(cv[jj].w, cv[jj].w, csq[jj]);
            }
#pragma unroll
            for (int ii = 0; ii < 8; ++ii)
#pragma unroll
                for (int jj = 0; jj < 8; ++jj) {
                    acc[ii][jj] = fmaf(xv[ii].x, cv[jj].x, acc[ii][jj]);
                    acc[ii][jj] = fmaf(xv[ii].y, cv[jj].y, acc[ii][jj]);
                    acc[ii][jj] = fmaf(xv[ii].z, cv[jj].z, acc[ii][jj]);
                    acc[ii][jj] = fmaf(xv[ii].w, cv[jj].w, acc[ii][jj]);
                }
        }

        // tile epilogue: score = cbsq - 2*dot (xsq constant per token -> irrelevant to argmin)
        // jj ascending => n ascending; strict < keeps FIRST min (numpy argmin rule)
#pragma unroll
        for (int jj = 0; jj < 8; ++jj) {
            const int n = nt * NT + ty + 16 * jj;
#pragma unroll
            for (int ii = 0; ii < 8; ++ii) {
                const float s = fmaf(-2.f, acc[ii][jj], csq[jj]);
                if (s < best[ii]) { best[ii] = s; bidx[ii] = n; }
            }
        }
    }

    __syncthreads();   // done with xs/cs; alias as reduction scratch
#pragma unroll
    for (int ii = 0; ii < 8; ++ii) {
        const int m = tx + 16 * ii;
        rs[ty][m] = best[ii];
        ri[ty][m] = bidx[ii];
    }
    __syncthreads();

    if (tid < MT) {
        const int m = tid;
        float b  = rs[0][m];
        int   bi = ri[0][m];
#pragma unroll
        for (int j = 1; j < 16; ++j) {
            const float s  = rs[j][m];
            const int   i2 = ri[j][m];
            if (s < b || (s == b && i2 < bi)) { b = s; bi = i2; }
        }
        bfin[m] = bi;
    }
    __syncthreads();

    // ---- gather: out[token, c*64 : c*64+64] = codebook[c, bfin[m], :]  (K=1)
    {
        float4* og = reinterpret_cast<float4*>(out);
#pragma unroll
        for (int i = 0; i < 8; ++i) {
            const int flat = i * 256 + tid;      // 0..2047 quads
            const int m    = flat >> 4;
            const int q    = flat & 15;
            const int n    = bfin[m];
            og[(size_t)(mbase + m) * (DTOT / 4) + c * K4 + q] =
                cg[((size_t)c * NCODE + n) * K4 + q];
        }
    }
}

extern "C" void kernel_launch(void* const* d_in, const int* in_sizes, int n_in,
                              void* d_out, int out_size, void* d_ws, size_t ws_size,
                              hipStream_t stream)
{
    const float* x  = (const float*)d_in[0];
    const float* cb = (const float*)d_in[1];
    float* out      = (float*)d_out;

    dim3 grid(BS / MT, CCH);   // 64 x 16
    vq_argmin_gather<<<grid, 256, 0, stream>>>(x, cb, out);
}

// Round 2
// 515.412 us; speedup vs baseline: 1.0585x; 1.0585x over previous
//
#include <hip/hip_runtime.h>

// Problem constants (B=4, S=2048, D=1024, C=16, N=2048, sub=64, K=1)
constexpr int BS    = 8192;   // B*S tokens
constexpr int DTOT  = 1024;
constexpr int CCH   = 16;     // chunks
constexpr int NCODE = 2048;   // codewords per chunk
constexpr int SUB   = 64;     // sub-dim
constexpr int K4    = SUB / 4;

constexpr int MT = 128;       // token tile
constexpr int NT = 128;       // codeword tile

typedef float f2 __attribute__((ext_vector_type(2)));
__device__ __forceinline__ f2 pkfma(f2 a, f2 b, f2 c) {
    return __builtin_elementwise_fma(a, b, c);   // -> v_pk_fma_f32 on gfx950
}

// XOR swizzle: row stride is 128 float4 = 512 dwords (== 0 mod 32 banks).
// Swizzling the column by k4's low 3 bits spreads the 16 k4-rows across all
// 8 bank groups -> 2-way aliasing (free) instead of 16-way write conflicts.
#define SW(m, k4) ((m) ^ ((k4) & 7))

// ---------- prologue: cbsq[c][n] = ||codebook[c][n]||^2 ----------
__global__ void cbsq_kernel(const float* __restrict__ cb, float* __restrict__ cbsq)
{
    const int g = blockIdx.x * 256 + threadIdx.x;   // 0 .. C*N-1
    const float4* cg = reinterpret_cast<const float4*>(cb);
    float s = 0.f;
#pragma unroll
    for (int q = 0; q < K4; ++q) {
        float4 v = cg[(size_t)g * K4 + q];
        s = fmaf(v.x, v.x, s);
        s = fmaf(v.y, v.y, s);
        s = fmaf(v.z, v.z, s);
        s = fmaf(v.w, v.w, s);
    }
    cbsq[g] = s;
}

// ---------- main: fused distance-GEMM + argmin + gather ----------
__global__ __launch_bounds__(256, 2)
void vq_argmin_gather(const float* __restrict__ x,
                      const float* __restrict__ cb,
                      const float* __restrict__ cbsq,
                      float* __restrict__ out)
{
    __shared__ __align__(16) char smraw[65536];
    float4 (*xs)[MT] = reinterpret_cast<float4(*)[MT]>(smraw);
    float4 (*cs)[NT] = reinterpret_cast<float4(*)[NT]>(smraw + 32768);
    float  (*rs)[MT] = reinterpret_cast<float(*)[MT]>(smraw);
    int    (*ri)[MT] = reinterpret_cast<int(*)[MT]>(smraw + 8192);
    int    *bfin     = reinterpret_cast<int*>(smraw + 16384);

    const int tid   = threadIdx.x;
    const int tx    = tid & 15;       // token-column group
    const int ty    = tid >> 4;       // codeword-column group
    const int c     = blockIdx.y;
    const int mbase = blockIdx.x * MT;

    const float4* xg = reinterpret_cast<const float4*>(x);
    const float4* cg = reinterpret_cast<const float4*>(cb);

    // ---- stage x tile (swizzled)
    {
        const int k4    = tid & 15;
        const int mrow0 = tid >> 4;
#pragma unroll
        for (int i = 0; i < 8; ++i) {
            const int m = i * 16 + mrow0;
            xs[k4][SW(m, k4)] = xg[(size_t)(mbase + m) * (DTOT / 4) + c * K4 + k4];
        }
    }

    float best[8];
    int   bidx[8];
#pragma unroll
    for (int ii = 0; ii < 8; ++ii) { best[ii] = 3.4e38f; bidx[ii] = 0; }

    for (int nt = 0; nt < NCODE / NT; ++nt) {
        __syncthreads();   // previous tile's readers done before overwrite
        // ---- stage codeword tile (swizzled)
        {
            const int k4    = tid & 15;
            const int nrow0 = tid >> 4;
#pragma unroll
            for (int i = 0; i < 8; ++i) {
                const int n = i * 16 + nrow0;
                cs[k4][SW(n, k4)] = cg[((size_t)c * NCODE + nt * NT + n) * K4 + k4];
            }
        }
        // issue codeword-norm loads early (L2-hot, overlap with staging)
        float sq[8];
#pragma unroll
        for (int jj = 0; jj < 8; ++jj)
            sq[jj] = cbsq[c * NCODE + nt * NT + ty + 16 * jj];
        __syncthreads();

        f2 acc[8][8];
#pragma unroll
        for (int ii = 0; ii < 8; ++ii)
#pragma unroll
            for (int jj = 0; jj < 8; ++jj) acc[ii][jj] = f2{0.f, 0.f};

#pragma unroll 2
        for (int k4 = 0; k4 < K4; ++k4) {
            float4 xv[8], cv[8];
#pragma unroll
            for (int ii = 0; ii < 8; ++ii) xv[ii] = xs[k4][SW(tx + 16 * ii, k4)];
#pragma unroll
            for (int jj = 0; jj < 8; ++jj) cv[jj] = cs[k4][SW(ty + 16 * jj, k4)];

#pragma unroll
            for (int ii = 0; ii < 8; ++ii) {
                const f2 xlo = {xv[ii].x, xv[ii].y};
                const f2 xhi = {xv[ii].z, xv[ii].w};
#pragma unroll
                for (int jj = 0; jj < 8; ++jj) {
                    const f2 clo = {cv[jj].x, cv[jj].y};
                    const f2 chi = {cv[jj].z, cv[jj].w};
                    acc[ii][jj] = pkfma(xlo, clo, acc[ii][jj]);
                    acc[ii][jj] = pkfma(xhi, chi, acc[ii][jj]);
                }
            }
        }

        // tile epilogue: score = cbsq - 2*dot (xsq constant per token)
        // jj ascending => n ascending; strict < keeps FIRST min (numpy rule)
#pragma unroll
        for (int jj = 0; jj < 8; ++jj) {
            const int n = nt * NT + ty + 16 * jj;
#pragma unroll
            for (int ii = 0; ii < 8; ++ii) {
                const float dot = acc[ii][jj].x + acc[ii][jj].y;
                const float s = fmaf(-2.f, dot, sq[jj]);
                if (s < best[ii]) { best[ii] = s; bidx[ii] = n; }
            }
        }
    }

    __syncthreads();   // done with xs/cs; alias as reduction scratch
#pragma unroll
    for (int ii = 0; ii < 8; ++ii) {
        const int m = tx + 16 * ii;
        rs[ty][m] = best[ii];
        ri[ty][m] = bidx[ii];
    }
    __syncthreads();

    if (tid < MT) {
        const int m = tid;
        float b  = rs[0][m];
        int   bi = ri[0][m];
#pragma unroll
        for (int j = 1; j < 16; ++j) {
            const float s  = rs[j][m];
            const int   i2 = ri[j][m];
            if (s < b || (s == b && i2 < bi)) { b = s; bi = i2; }
        }
        bfin[m] = bi;
    }
    __syncthreads();

    // ---- gather: out[token, c*64 : c*64+64] = codebook[c, bfin[m], :]  (K=1)
    {
        float4* og = reinterpret_cast<float4*>(out);
#pragma unroll
        for (int i = 0; i < 8; ++i) {
            const int flat = i * 256 + tid;      // 0..2047 quads
            const int m    = flat >> 4;
            const int q    = flat & 15;
            const int n    = bfin[m];
            og[(size_t)(mbase + m) * (DTOT / 4) + c * K4 + q] =
                cg[((size_t)c * NCODE + n) * K4 + q];
        }
    }
}

extern "C" void kernel_launch(void* const* d_in, const int* in_sizes, int n_in,
                              void* d_out, int out_size, void* d_ws, size_t ws_size,
                              hipStream_t stream)
{
    const float* x  = (const float*)d_in[0];
    const float* cb = (const float*)d_in[1];
    float* out      = (float*)d_out;
    float* cbsq     = (float*)d_ws;   // C*N floats = 128 KB

    cbsq_kernel<<<CCH * NCODE / 256, 256, 0, stream>>>(cb, cbsq);

    dim3 grid(BS / MT, CCH);   // 64 x 16
    vq_argmin_gather<<<grid, 256, 0, stream>>>(x, cb, cbsq, out);
}